// Round 3
// baseline (65.973 us; speedup 1.0000x reference)
//
#include <hip/hip_runtime.h>
#include <math.h>

#define HID 2048
#define EMB 512
#define NV 16

__device__ __forceinline__ float dot4(float4 a, float4 b) {
    return a.x * b.x + a.y * b.y + a.z * b.z + a.w * b.w;
}

__device__ __forceinline__ float wred(float v) {
#pragma unroll
    for (int o = 32; o >= 1; o >>= 1) v += __shfl_down(v, o, 64);
    return v;
}

__device__ __forceinline__ float sig(float x) { return 1.0f / (1.0f + __expf(-x)); }

// k1: blocks 0..1023 -> h0 rows (2 rows/block); blocks 1024..2047 -> gh1 rows (2 rows/block)
// Each block: 256 threads = 2 halves of 128; half handles one output row, 4 chunks/stream.
__global__ __launch_bounds__(256) void k1(
    const int* __restrict__ xidx,
    const float* __restrict__ h_in,
    const float* __restrict__ emb,
    const float* __restrict__ w_ih0,
    const float* __restrict__ w_hh0,
    const float* __restrict__ b_ih0,
    const float* __restrict__ b_hh0,
    const float* __restrict__ w_hh1,
    const float* __restrict__ b_hh1,
    float* __restrict__ out,
    float* __restrict__ ws)
{
    const int tid  = threadIdx.x;
    const int t    = tid & 127;   // lane within half
    const int half = tid >> 7;    // which output row
    const int wave = tid >> 6;
    const int lane = tid & 63;
    const int bid  = blockIdx.x;
    __shared__ float red[4][4];

    if (bid == 0 && tid == 0) ((int*)ws)[3 * HID] = 0;  // zero k2's completion counter

    if (bid < 1024) {
        const int j = 2 * bid + half;
        const float bi_r = b_ih0[j];
        const float bi_z = b_ih0[j + HID];
        const float bi_n = b_ih0[j + 2 * HID];
        const float bh_r = b_hh0[j];
        const float bh_z = b_hh0[j + HID];
        const float bh_n = b_hh0[j + 2 * HID];
        const float hprev = h_in[j];

        const float4* hv = (const float4*)h_in;                       // h_in[0]
        const float4* wr = (const float4*)(w_hh0 + (size_t)j * HID);
        const float4* wz = (const float4*)(w_hh0 + (size_t)(j + HID) * HID);
        const float4* wn = (const float4*)(w_hh0 + (size_t)(j + 2 * HID) * HID);
        const float4* ev = (const float4*)(emb + (size_t)xidx[0] * EMB);
        const float4* pir = (const float4*)(w_ih0 + (size_t)j * EMB);
        const float4* piz = (const float4*)(w_ih0 + (size_t)(j + HID) * EMB);
        const float4* pin = (const float4*)(w_ih0 + (size_t)(j + 2 * HID) * EMB);

        // 20 independent float4 loads in flight per thread
        float4 x0 = hv[t], x1 = hv[t + 128], x2 = hv[t + 256], x3 = hv[t + 384];
        float4 r0 = wr[t], r1 = wr[t + 128], r2 = wr[t + 256], r3 = wr[t + 384];
        float4 z0 = wz[t], z1 = wz[t + 128], z2 = wz[t + 256], z3 = wz[t + 384];
        float4 n0 = wn[t], n1 = wn[t + 128], n2 = wn[t + 256], n3 = wn[t + 384];
        float4 e4 = ev[t];
        float4 i0 = pir[t], i1 = piz[t], i2 = pin[t];

        // r,z gates: ih + hh parts add linearly -> shared accumulators
        float s_r  = dot4(r0, x0) + dot4(r1, x1) + dot4(r2, x2) + dot4(r3, x3) + dot4(i0, e4);
        float s_z  = dot4(z0, x0) + dot4(z1, x1) + dot4(z2, x2) + dot4(z3, x3) + dot4(i1, e4);
        float s_hn = dot4(n0, x0) + dot4(n1, x1) + dot4(n2, x2) + dot4(n3, x3);
        float s_in = dot4(i2, e4);

        s_r = wred(s_r); s_z = wred(s_z); s_hn = wred(s_hn); s_in = wred(s_in);
        if (lane == 0) {
            red[wave][0] = s_r; red[wave][1] = s_z; red[wave][2] = s_hn; red[wave][3] = s_in;
        }
        __syncthreads();
        if (t == 0) {  // tid 0 (half 0) and tid 128 (half 1)
            const int w0 = 2 * half, w1 = 2 * half + 1;
            float r  = sig(red[w0][0] + red[w1][0] + bi_r + bh_r);
            float z  = sig(red[w0][1] + red[w1][1] + bi_z + bh_z);
            float hn = red[w0][2] + red[w1][2] + bh_n;
            float n  = tanhf(red[w0][3] + red[w1][3] + bi_n + r * hn);
            out[NV + j] = (1.0f - z) * n + z * hprev;
        }
    } else {
        const int j = 2 * (bid - 1024) + half;
        const float b_r = b_hh1[j];
        const float b_z = b_hh1[j + HID];
        const float b_n = b_hh1[j + 2 * HID];

        const float4* hv = (const float4*)(h_in + HID);               // h_in[1]
        const float4* wr = (const float4*)(w_hh1 + (size_t)j * HID);
        const float4* wz = (const float4*)(w_hh1 + (size_t)(j + HID) * HID);
        const float4* wn = (const float4*)(w_hh1 + (size_t)(j + 2 * HID) * HID);

        float4 x0 = hv[t], x1 = hv[t + 128], x2 = hv[t + 256], x3 = hv[t + 384];
        float4 r0 = wr[t], r1 = wr[t + 128], r2 = wr[t + 256], r3 = wr[t + 384];
        float4 z0 = wz[t], z1 = wz[t + 128], z2 = wz[t + 256], z3 = wz[t + 384];
        float4 n0 = wn[t], n1 = wn[t + 128], n2 = wn[t + 256], n3 = wn[t + 384];

        float s_r = dot4(r0, x0) + dot4(r1, x1) + dot4(r2, x2) + dot4(r3, x3);
        float s_z = dot4(z0, x0) + dot4(z1, x1) + dot4(z2, x2) + dot4(z3, x3);
        float s_n = dot4(n0, x0) + dot4(n1, x1) + dot4(n2, x2) + dot4(n3, x3);

        s_r = wred(s_r); s_z = wred(s_z); s_n = wred(s_n);
        if (lane == 0) {
            red[wave][0] = s_r; red[wave][1] = s_z; red[wave][2] = s_n;
        }
        __syncthreads();
        if (t == 0) {
            const int w0 = 2 * half, w1 = 2 * half + 1;
            ws[j]           = red[w0][0] + red[w1][0] + b_r;
            ws[j + HID]     = red[w0][1] + red[w1][1] + b_z;
            ws[j + 2 * HID] = red[w0][2] + red[w1][2] + b_n;
        }
    }
}

// k2: gi1 = w_ih1 @ h0 + b_ih1; combine with gh1 -> h1. Last finishing block computes
// head logits + softmax (k3 fused via device-scope atomic completion counter).
__global__ __launch_bounds__(256) void k2(
    const float* __restrict__ h_in,
    const float* __restrict__ w_ih1,
    const float* __restrict__ b_ih1,
    const float* __restrict__ w_head,
    const float* __restrict__ b_head,
    float* __restrict__ out,
    float* __restrict__ ws)
{
    const int tid  = threadIdx.x;
    const int t    = tid & 127;
    const int half = tid >> 7;
    const int wave = tid >> 6;
    const int lane = tid & 63;
    const int bid  = blockIdx.x;
    __shared__ float red[4][3];
    __shared__ int lastFlag;
    __shared__ float logits[NV];

    const int j = 2 * bid + half;
    const float bi_r = b_ih1[j];
    const float bi_z = b_ih1[j + HID];
    const float bi_n = b_ih1[j + 2 * HID];
    const float g_r  = ws[j];
    const float g_z  = ws[j + HID];
    const float g_n  = ws[j + 2 * HID];
    const float hprev = h_in[HID + j];

    const float4* hv = (const float4*)(out + NV);                     // h0 from k1
    const float4* wr = (const float4*)(w_ih1 + (size_t)j * HID);
    const float4* wz = (const float4*)(w_ih1 + (size_t)(j + HID) * HID);
    const float4* wn = (const float4*)(w_ih1 + (size_t)(j + 2 * HID) * HID);

    float4 x0 = hv[t], x1 = hv[t + 128], x2 = hv[t + 256], x3 = hv[t + 384];
    float4 r0 = wr[t], r1 = wr[t + 128], r2 = wr[t + 256], r3 = wr[t + 384];
    float4 z0 = wz[t], z1 = wz[t + 128], z2 = wz[t + 256], z3 = wz[t + 384];
    float4 n0 = wn[t], n1 = wn[t + 128], n2 = wn[t + 256], n3 = wn[t + 384];

    float s_r = dot4(r0, x0) + dot4(r1, x1) + dot4(r2, x2) + dot4(r3, x3);
    float s_z = dot4(z0, x0) + dot4(z1, x1) + dot4(z2, x2) + dot4(z3, x3);
    float s_n = dot4(n0, x0) + dot4(n1, x1) + dot4(n2, x2) + dot4(n3, x3);

    s_r = wred(s_r); s_z = wred(s_z); s_n = wred(s_n);
    if (lane == 0) { red[wave][0] = s_r; red[wave][1] = s_z; red[wave][2] = s_n; }
    __syncthreads();
    if (t == 0) {
        const int w0 = 2 * half, w1 = 2 * half + 1;
        float r = sig(red[w0][0] + red[w1][0] + bi_r + g_r);
        float z = sig(red[w0][1] + red[w1][1] + bi_z + g_z);
        float n = tanhf(red[w0][2] + red[w1][2] + bi_n + r * g_n);
        out[NV + HID + j] = (1.0f - z) * n + z * hprev;
    }
    __syncthreads();

    if (tid == 0) {
        __threadfence();                                   // release our h1 stores
        int* cnt = (int*)ws + 3 * HID;
        int old = atomicAdd(cnt, 1);                       // device-scope
        lastFlag = (old == (int)gridDim.x - 1);
    }
    __syncthreads();
    if (!lastFlag) return;

    // ---- fused head (only the last block reaches here; all 1023 others fenced first) ----
    __threadfence();                                       // acquire others' h1 stores
    const int row = tid >> 4;   // 0..15
    const int sub = tid & 15;
    const float bh = b_head[row];
    const float4* h1v = (const float4*)(out + NV + HID);
    const float4* w   = (const float4*)(w_head + (size_t)row * HID);

    float s = 0.f;
#pragma unroll 8
    for (int c = sub; c < HID / 4; c += 16) s += dot4(w[c], h1v[c]);
#pragma unroll
    for (int o = 8; o >= 1; o >>= 1) s += __shfl_down(s, o, 16);

    if (sub == 0) logits[row] = s + bh;
    __syncthreads();
    if (tid == 0) {
        float m = logits[0];
#pragma unroll
        for (int i = 1; i < NV; ++i) m = fmaxf(m, logits[i]);
        float ex[NV]; float den = 0.f;
#pragma unroll
        for (int i = 0; i < NV; ++i) { ex[i] = __expf(logits[i] - m); den += ex[i]; }
        float inv = 1.0f / den;
#pragma unroll
        for (int i = 0; i < NV; ++i) out[i] = ex[i] * inv;
    }
}

extern "C" void kernel_launch(void* const* d_in, const int* in_sizes, int n_in,
                              void* d_out, int out_size, void* d_ws, size_t ws_size,
                              hipStream_t stream) {
    const int*   x      = (const int*)  d_in[0];
    const float* h_in   = (const float*)d_in[1];
    const float* emb    = (const float*)d_in[2];
    const float* w_ih0  = (const float*)d_in[3];
    const float* w_hh0  = (const float*)d_in[4];
    const float* b_ih0  = (const float*)d_in[5];
    const float* b_hh0  = (const float*)d_in[6];
    const float* w_ih1  = (const float*)d_in[7];
    const float* w_hh1  = (const float*)d_in[8];
    const float* b_ih1  = (const float*)d_in[9];
    const float* b_hh1  = (const float*)d_in[10];
    const float* w_head = (const float*)d_in[11];
    const float* b_head = (const float*)d_in[12];
    float* out = (float*)d_out;
    float* ws  = (float*)d_ws;   // [0..6143]=gh1, int slot at 6144 = completion counter

    k1<<<2048, 256, 0, stream>>>(x, h_in, emb, w_ih0, w_hh0, b_ih0, b_hh0,
                                 w_hh1, b_hh1, out, ws);
    k2<<<1024, 256, 0, stream>>>(h_in, w_ih1, b_ih1, w_head, b_head, out, ws);
}